// Round 13
// baseline (541.679 us; speedup 1.0000x reference)
//
#include <hip/hip_runtime.h>
#include <hip/hip_bf16.h>
#include <math.h>

// Problem constants (from the reference)
#define BS    4
#define QLEN  2048
#define DIM   1024
#define NH    16
#define DH    64
#define MROWS (BS * QLEN)          // 8192 rows in the projection GEMMs

typedef short  bf16x8 __attribute__((ext_vector_type(8)));  // 8 bf16 (4 VGPRs)
typedef short  bf16x4 __attribute__((ext_vector_type(4)));  // 4 bf16 (8B)
typedef float  f32x4  __attribute__((ext_vector_type(4)));  // MFMA acc

// float -> bf16 (round-to-nearest-even), bit pattern in a short
static __device__ __forceinline__ short f2bf(float f) {
    union { float f; unsigned u; } x; x.f = f;
    unsigned r = (x.u + 0x7fffu + ((x.u >> 16) & 1u)) >> 16;
    return (short)r;
}

// pack 2 floats -> 2 bf16 in one uint via v_cvt_pk_bf16_f32 (RNE)
static __device__ __forceinline__ unsigned pk2bf(float lo, float hi) {
    union { __hip_bfloat162 h; unsigned u; } cv;
    cv.h = __float22bfloat162_rn(make_float2(lo, hi));
    return cv.u;
}

// ---------------------------------------------------------------------------
// Prepass: convert x and the 4 weight matrices fp32 -> bf16 once.
// ---------------------------------------------------------------------------
__global__ __launch_bounds__(256)
void cvt_bf16_all(const float* __restrict__ x,
                  const float* __restrict__ wq, const float* __restrict__ wk,
                  const float* __restrict__ wv, const float* __restrict__ wo,
                  short* __restrict__ xb, short* __restrict__ wqb,
                  short* __restrict__ wkb, short* __restrict__ wvb,
                  short* __restrict__ wob)
{
    const float* src; short* dst; int n;
    switch (blockIdx.y) {
        case 0:  src = x;  dst = xb;  n = MROWS * DIM; break;
        case 1:  src = wq; dst = wqb; n = DIM * DIM;   break;
        case 2:  src = wk; dst = wkb; n = DIM * DIM;   break;
        case 3:  src = wv; dst = wvb; n = DIM * DIM;   break;
        default: src = wo; dst = wob; n = DIM * DIM;   break;
    }
    for (int i = (blockIdx.x * 256 + threadIdx.x) * 8; i < n;
         i += gridDim.x * 256 * 8) {
        float4 a = *reinterpret_cast<const float4*>(src + i);
        float4 b = *reinterpret_cast<const float4*>(src + i + 4);
        bf16x8 t;
        t[0] = f2bf(a.x); t[1] = f2bf(a.y); t[2] = f2bf(a.z); t[3] = f2bf(a.w);
        t[4] = f2bf(b.x); t[5] = f2bf(b.y); t[6] = f2bf(b.z); t[7] = f2bf(b.w);
        *reinterpret_cast<bf16x8*>(dst + i) = t;
    }
}

// ===========================================================================
// bf16-MFMA GEMM core with register prefetch (hide global latency).
// C(128x128) = A(128xK) . B(128xK)^T, A,B bf16 in HBM. BK=64.
// LDS [128][72] (144B stride -> <=2-way bank conflicts on b128 frag reads).
// 4 waves (2x2); wave (wr,wc) owns a 64x64 quadrant as 4x4 MFMA fragments.
// MFMA 16x16x32 layouts: a[j]=A[l&15][(l>>4)*8+j], b[j]=Bs[l&15][(l>>4)*8+j],
// d[r]=D[(l>>4)*4+r][l&15].
// ===========================================================================
#define GEMM_CORE_BF16(APTR, BPTR)                                            \
    __shared__ short As[128][72];                                             \
    __shared__ short Bs[128][72];                                             \
    const int tid  = threadIdx.x;                                             \
    const int w    = tid >> 6;                                                \
    const int l    = tid & 63;                                                \
    const int g    = l >> 4;                                                  \
    const int l15  = l & 15;                                                  \
    const int wr   = w >> 1;                                                  \
    const int wc   = w & 1;                                                   \
    const int m0   = blockIdx.x * 128;                                        \
    const int n0   = blockIdx.y * 128;                                        \
    const int srow = tid >> 3;           /* 0..31 */                          \
    const int scol = (tid & 7) * 8;      /* 0..56, 16B-aligned */             \
    bf16x8 ra[4], rb[4];                                                      \
    _Pragma("unroll")                                                         \
    for (int it = 0; it < 4; ++it) {                                          \
        const int row = it * 32 + srow;                                       \
        ra[it] = *reinterpret_cast<const bf16x8*>(                            \
            &APTR[(size_t)(m0 + row) * DIM + scol]);                          \
        rb[it] = *reinterpret_cast<const bf16x8*>(                            \
            &BPTR[(size_t)(n0 + row) * DIM + scol]);                          \
    }                                                                         \
    f32x4 acc[4][4];                                                          \
    _Pragma("unroll")                                                         \
    for (int m = 0; m < 4; ++m)                                               \
        _Pragma("unroll")                                                     \
        for (int n = 0; n < 4; ++n) acc[m][n] = (f32x4){0.f, 0.f, 0.f, 0.f}; \
    for (int k0 = 0; k0 < DIM; k0 += 64) {                                    \
        __syncthreads();                                                      \
        _Pragma("unroll")                                                     \
        for (int it = 0; it < 4; ++it) {                                      \
            const int row = it * 32 + srow;                                   \
            *reinterpret_cast<bf16x8*>(&As[row][scol]) = ra[it];              \
            *reinterpret_cast<bf16x8*>(&Bs[row][scol]) = rb[it];              \
        }                                                                     \
        if (k0 + 64 < DIM) {                                                  \
            _Pragma("unroll")                                                 \
            for (int it = 0; it < 4; ++it) {                                  \
                const int row = it * 32 + srow;                               \
                ra[it] = *reinterpret_cast<const bf16x8*>(                    \
                    &APTR[(size_t)(m0 + row) * DIM + k0 + 64 + scol]);        \
                rb[it] = *reinterpret_cast<const bf16x8*>(                    \
                    &BPTR[(size_t)(n0 + row) * DIM + k0 + 64 + scol]);        \
            }                                                                 \
        }                                                                     \
        __syncthreads();                                                      \
        _Pragma("unroll")                                                     \
        for (int ks = 0; ks < 2; ++ks) {                                      \
            bf16x8 af[4], bfv[4];                                             \
            _Pragma("unroll")                                                 \
            for (int m = 0; m < 4; ++m)                                       \
                af[m] = *reinterpret_cast<const bf16x8*>(                     \
                    &As[wr * 64 + m * 16 + l15][ks * 32 + g * 8]);            \
            _Pragma("unroll")                                                 \
            for (int n = 0; n < 4; ++n)                                       \
                bfv[n] = *reinterpret_cast<const bf16x8*>(                    \
                    &Bs[wc * 64 + n * 16 + l15][ks * 32 + g * 8]);            \
            _Pragma("unroll")                                                 \
            for (int m = 0; m < 4; ++m)                                       \
                _Pragma("unroll")                                             \
                for (int n = 0; n < 4; ++n)                                   \
                    acc[m][n] = __builtin_amdgcn_mfma_f32_16x16x32_bf16(      \
                        af[m], bfv[n], acc[m][n], 0, 0, 0);                   \
        }                                                                     \
    }

// ---------------------------------------------------------------------------
// Fused QKV projection: out = (x @ W^T + b) [* scale for Q], written as
// bf16 scattered into per-head layout [b][h][q][d]. blockIdx.z selects Q/K/V.
// Q scale folds log2(e) so flash softmax can use exp2 directly:
//   exp(s - m) == exp2(s' - m') with s' = s*log2e  (exact).
// ---------------------------------------------------------------------------
__global__ __launch_bounds__(256, 2)
void gemm_qkv_mfma(const short* __restrict__ xb,
                   const short* __restrict__ wqb, const float* __restrict__ bq,
                   const short* __restrict__ wkb, const float* __restrict__ bk,
                   const short* __restrict__ wvb, const float* __restrict__ bv,
                   short* __restrict__ qout, short* __restrict__ kout,
                   short* __restrict__ vout)
{
    const int which = blockIdx.z;
    const short* __restrict__ W    = (which == 0) ? wqb : (which == 1) ? wkb : wvb;
    const float* __restrict__ bias = (which == 0) ? bq  : (which == 1) ? bk  : bv;
    short* __restrict__ out        = (which == 0) ? qout : (which == 1) ? kout : vout;
    // Q: 1/sqrt(64) * log2(e) = 0.125 * 1.4426950408889634
    const float scale = (which == 0) ? 0.18033688011112043f : 1.0f;

    GEMM_CORE_BF16(xb, W)

    // epilogue: bias + scale, bf16 scatter to [b][h][q][d]
    const int h = (n0 + wc * 64) >> 6;     // head is constant per wave quadrant
    #pragma unroll
    for (int n = 0; n < 4; ++n) {
        const int dd = n * 16 + l15;
        const float bn = bias[(h << 6) + dd];
        #pragma unroll
        for (int m = 0; m < 4; ++m) {
            #pragma unroll
            for (int r = 0; r < 4; ++r) {
                const int row = m0 + wr * 64 + m * 16 + g * 4 + r;
                const int bb  = row >> 11;           // / QLEN
                const int qq  = row & (QLEN - 1);
                out[(((size_t)bb * NH + h) * QLEN + qq) * DH + dd] =
                    f2bf((acc[m][n][r] + bn) * scale);
            }
        }
    }
}

// ---------------------------------------------------------------------------
// Output projection: out = ctx @ wo^T + bo  (ctx bf16, out fp32 row-major)
// ---------------------------------------------------------------------------
__global__ __launch_bounds__(256, 2)
void gemm_out_mfma(const short* __restrict__ A,
                   const short* __restrict__ W, const float* __restrict__ bias,
                   float* __restrict__ out)
{
    GEMM_CORE_BF16(A, W)

    #pragma unroll
    for (int n = 0; n < 4; ++n) {
        const int col  = n0 + wc * 64 + n * 16 + l15;
        const float bn = bias[col];
        #pragma unroll
        for (int m = 0; m < 4; ++m) {
            #pragma unroll
            for (int r = 0; r < 4; ++r) {
                const int row = m0 + wr * 64 + m * 16 + g * 4 + r;
                out[(size_t)row * DIM + col] = acc[m][n][r] + bn;
            }
        }
    }
}

// ===========================================================================
// Flash attention, bf16 MFMA, fp32 accumulate, online softmax (base-2:
// scores arrive pre-scaled by log2e, so exp2 == exp -- single v_exp_f32).
// 128 q-rows/block (two 16-row halves per wave, separate Ps buffers).
// P -> bf16 via packed v_cvt_pk_bf16_f32. Register-prefetched K/V staging.
// XCD-swizzled 1D grid: each XCD serves 8 consecutive heads -> K/V working
// set 4MB = one L2.
// ===========================================================================
#define FLASH_HALF(QB, O, MREG, LREG, PS)                                     \
    {                                                                         \
        f32x4 s_[4];                                                          \
        _Pragma("unroll")                                                     \
        for (int mf = 0; mf < 4; ++mf) s_[mf] = (f32x4){0.f, 0.f, 0.f, 0.f};  \
        _Pragma("unroll")                                                     \
        for (int mf = 0; mf < 4; ++mf) {                                      \
            _Pragma("unroll")                                                 \
            for (int ks = 0; ks < 2; ++ks) {                                  \
                bf16x8 a_ = *reinterpret_cast<const bf16x8*>(                 \
                    &Ks[mf * 16 + l15][ks * 32 + g * 8]);                     \
                s_[mf] = __builtin_amdgcn_mfma_f32_16x16x32_bf16(             \
                    a_, QB[ks], s_[mf], 0, 0, 0);                             \
            }                                                                 \
        }                                                                     \
        float pm_ = -1e30f;                                                   \
        _Pragma("unroll")                                                     \
        for (int mf = 0; mf < 4; ++mf)                                        \
            _Pragma("unroll")                                                 \
            for (int r = 0; r < 4; ++r) {                                     \
                s_[mf][r] += mneg[mf * 16 + g * 4 + r];                       \
                pm_ = fmaxf(pm_, s_[mf][r]);                                  \
            }                                                                 \
        pm_ = fmaxf(pm_, __shfl_xor(pm_, 16));                                \
        pm_ = fmaxf(pm_, __shfl_xor(pm_, 32));                                \
        const float mnew_ = fmaxf(MREG, pm_);                                 \
        const float resc_ = __builtin_amdgcn_exp2f(MREG - mnew_);             \
        float ps_ = 0.f;                                                      \
        _Pragma("unroll")                                                     \
        for (int mf = 0; mf < 4; ++mf) {                                      \
            const float p0_ = __builtin_amdgcn_exp2f(s_[mf][0] - mnew_);      \
            const float p1_ = __builtin_amdgcn_exp2f(s_[mf][1] - mnew_);      \
            const float p2_ = __builtin_amdgcn_exp2f(s_[mf][2] - mnew_);      \
            const float p3_ = __builtin_amdgcn_exp2f(s_[mf][3] - mnew_);      \
            ps_ += (p0_ + p1_) + (p2_ + p3_);                                 \
            uint2 pu_;                                                        \
            pu_.x = pk2bf(p0_, p1_);                                          \
            pu_.y = pk2bf(p2_, p3_);                                          \
            *reinterpret_cast<uint2*>(&PS[w][l15][mf * 16 + g * 4]) = pu_;    \
        }                                                                     \
        ps_ += __shfl_xor(ps_, 16);                                           \
        ps_ += __shfl_xor(ps_, 32);                                           \
        LREG = LREG * resc_ + ps_;                                            \
        MREG = mnew_;                                                         \
        float rs_[4];                                                         \
        _Pragma("unroll")                                                     \
        for (int r = 0; r < 4; ++r) rs_[r] = __shfl(resc_, g * 4 + r, 16);    \
        _Pragma("unroll")                                                     \
        for (int n = 0; n < 4; ++n)                                           \
            _Pragma("unroll")                                                 \
            for (int r = 0; r < 4; ++r) O[n][r] *= rs_[r];                    \
        asm volatile("s_waitcnt lgkmcnt(0)" ::: "memory");                    \
        __builtin_amdgcn_sched_barrier(0);                                    \
        _Pragma("unroll")                                                     \
        for (int ks = 0; ks < 2; ++ks) {                                      \
            bf16x8 pa_ = *reinterpret_cast<const bf16x8*>(                    \
                &PS[w][l15][ks * 32 + g * 8]);                                \
            _Pragma("unroll")                                                 \
            for (int n = 0; n < 4; ++n) {                                     \
                bf16x8 vb_ = *reinterpret_cast<const bf16x8*>(                \
                    &Vt[n * 16 + l15][ks * 32 + g * 8]);                      \
                O[n] = __builtin_amdgcn_mfma_f32_16x16x32_bf16(               \
                    pa_, vb_, O[n], 0, 0, 0);                                 \
            }                                                                 \
        }                                                                     \
    }

__global__ __launch_bounds__(256, 4)
void flash_attn_mfma(const short* __restrict__ q, const short* __restrict__ k,
                     const short* __restrict__ v, const int* __restrict__ mask,
                     short* __restrict__ ctx)
{
    // XCD swizzle: 1024 blocks, 8 XCDs round-robin on linear id ->
    // swz gives XCD x the contiguous range [x*128, (x+1)*128) = heads 8x..8x+7
    const int orig = blockIdx.x;
    const int swz  = (orig & 7) * 128 + (orig >> 3);
    const int bh   = swz >> 4;            // 0..63
    const int b    = bh >> 4;             // / NH
    const int h    = bh & 15;             // % NH
    const int q0   = (swz & 15) * 128;
    const int tid = threadIdx.x;
    const int w   = tid >> 6;             // wave 0..3
    const int l   = tid & 63;             // lane
    const int g   = l >> 4;               // 0..3
    const int l15 = l & 15;

    __shared__ short Ks[64][72];          // K tile  [key][d]   bf16, padded
    __shared__ short Vt[64][72];          // V tile  [d][key]   bf16, padded
    __shared__ short PsA[4][16][72];      // per-wave P, half A
    __shared__ short PsB[4][16][72];      // per-wave P, half B
    __shared__ float mneg[64];            // 0 or -1e30 per key of this tile

    const short* __restrict__ Qh = q + (size_t)bh * QLEN * DH;
    const short* __restrict__ Kh = k + (size_t)bh * QLEN * DH;
    const short* __restrict__ Vh = v + (size_t)bh * QLEN * DH;

    // staging geometry
    const int krow0 = tid >> 3;           // K: rows krow0, krow0+32
    const int kcol  = (tid & 7) * 8;
    const int vr0   = (tid & 15) * 4;     // V: 4x4 block at (vr0, vc0)
    const int vc0   = (tid >> 4) * 4;

    // ---- Q B-fragments for both 16-row halves (held for whole kernel) ----
    bf16x8 qbA[2], qbB[2];
    {
        const short* qpA = Qh + (size_t)(q0 + w * 16 + l15) * DH;
        const short* qpB = qpA + (size_t)64 * DH;
        #pragma unroll
        for (int ks = 0; ks < 2; ++ks) {
            qbA[ks] = *reinterpret_cast<const bf16x8*>(qpA + ks * 32 + g * 8);
            qbB[ks] = *reinterpret_cast<const bf16x8*>(qpB + ks * 32 + g * 8);
        }
    }

    // ---- prefetch tile 0 into registers ----
    bf16x8 kr[2];
    bf16x4 vrg[4];
    int    mv = 0;
    #pragma unroll
    for (int it = 0; it < 2; ++it)
        kr[it] = *reinterpret_cast<const bf16x8*>(
            &Kh[(size_t)(it * 32 + krow0) * DH + kcol]);
    #pragma unroll
    for (int i = 0; i < 4; ++i)
        vrg[i] = *reinterpret_cast<const bf16x4*>(
            &Vh[(size_t)(vr0 + i) * DH + vc0]);
    if (tid < 64) mv = mask[b * QLEN + tid];

    f32x4 oA[4], oB[4];
    #pragma unroll
    for (int n = 0; n < 4; ++n) {
        oA[n] = (f32x4){0.f, 0.f, 0.f, 0.f};
        oB[n] = (f32x4){0.f, 0.f, 0.f, 0.f};
    }
    float mAx = -1e30f, lAx = 0.f;
    float mBx = -1e30f, lBx = 0.f;

    for (int kt = 0; kt < QLEN; kt += 64) {
        __syncthreads();   // previous tile's LDS reads complete

        // ---- write prefetched regs to LDS ----
        #pragma unroll
        for (int it = 0; it < 2; ++it)
            *reinterpret_cast<bf16x8*>(&Ks[it * 32 + krow0][kcol]) = kr[it];
        #pragma unroll
        for (int j = 0; j < 4; ++j) {
            bf16x4 wv = {vrg[0][j], vrg[1][j], vrg[2][j], vrg[3][j]};
            *reinterpret_cast<bf16x4*>(&Vt[vc0 + j][vr0]) = wv;
        }
        if (tid < 64) mneg[tid] = (mv == 0) ? -1e30f : 0.0f;

        // ---- issue next tile's global loads (latency hides under compute) --
        if (kt + 64 < QLEN) {
            #pragma unroll
            for (int it = 0; it < 2; ++it)
                kr[it] = *reinterpret_cast<const bf16x8*>(
                    &Kh[(size_t)(kt + 64 + it * 32 + krow0) * DH + kcol]);
            #pragma unroll
            for (int i = 0; i < 4; ++i)
                vrg[i] = *reinterpret_cast<const bf16x4*>(
                    &Vh[(size_t)(kt + 64 + vr0 + i) * DH + vc0]);
            if (tid < 64) mv = mask[b * QLEN + kt + 64 + tid];
        }
        __syncthreads();

        // ---- both 16-row halves, explicit names, separate Ps buffers ----
        FLASH_HALF(qbA, oA, mAx, lAx, PsA)
        FLASH_HALF(qbB, oB, mBx, lBx, PsB)
    }

    // ---- epilogue: normalize, write ctx (bf16) in [b][q][dim] ----
    {
        float ln[4];
        #pragma unroll
        for (int r = 0; r < 4; ++r) ln[r] = __shfl(lAx, g * 4 + r, 16);
        #pragma unroll
        for (int r = 0; r < 4; ++r) {
            const float inv  = 1.0f / ln[r];
            const int   qrow = q0 + w * 16 + g * 4 + r;
            #pragma unroll
            for (int n = 0; n < 4; ++n)
                ctx[((size_t)b * QLEN + qrow) * DIM + h * DH + n * 16 + l15] =
                    f2bf(oA[n][r] * inv);
        }
    }
    {
        float ln[4];
        #pragma unroll
        for (int r = 0; r < 4; ++r) ln[r] = __shfl(lBx, g * 4 + r, 16);
        #pragma unroll
        for (int r = 0; r < 4; ++r) {
            const float inv  = 1.0f / ln[r];
            const int   qrow = q0 + 64 + w * 16 + g * 4 + r;
            #pragma unroll
            for (int n = 0; n < 4; ++n)
                ctx[((size_t)b * QLEN + qrow) * DIM + h * DH + n * 16 + l15] =
                    f2bf(oB[n][r] * inv);
        }
    }
}

// ---------------------------------------------------------------------------
extern "C" void kernel_launch(void* const* d_in, const int* in_sizes, int n_in,
                              void* d_out, int out_size, void* d_ws, size_t ws_size,
                              hipStream_t stream)
{
    const float* x    = (const float*)d_in[0];
    const int*   mask = (const int*)  d_in[1];
    const float* wq   = (const float*)d_in[2];
    const float* bq   = (const float*)d_in[3];
    const float* wk   = (const float*)d_in[4];
    const float* bk   = (const float*)d_in[5];
    const float* wv   = (const float*)d_in[6];
    const float* bv   = (const float*)d_in[7];
    const float* wo   = (const float*)d_in[8];
    const float* bo   = (const float*)d_in[9];
    float* out = (float*)d_out;

    short* ws = (short*)d_ws;
    const size_t S  = (size_t)MROWS * DIM;     // 8.39M elements
    const size_t W2 = (size_t)DIM * DIM;       // 1.05M elements
    short* xb   = ws;
    short* wqb  = xb  + S;
    short* wkb  = wqb + W2;
    short* wvb  = wkb + W2;
    short* wob  = wvb + W2;
    short* qb   = wob + W2;
    short* kb   = qb  + S;
    short* vb   = kb  + S;
    short* ctxb = vb  + S;

    // 0) one-time fp32 -> bf16 conversion of x and weights
    dim3 gc(512, 5);
    cvt_bf16_all<<<gc, 256, 0, stream>>>(x, wq, wk, wv, wo,
                                         xb, wqb, wkb, wvb, wob);

    // 1) fused QKV projections (z selects Q/K/V), bf16 in/out
    dim3 gq(MROWS / 128, DIM / 128, 3);
    gemm_qkv_mfma<<<gq, 256, 0, stream>>>(xb, wqb, bq, wkb, bk, wvb, bv,
                                          qb, kb, vb);

    // 2) flash attention (bf16 MFMA, 128 q-rows/block, XCD-swizzled 1D grid)
    dim3 gf((QLEN / 128) * BS * NH);      // 1024 blocks
    flash_attn_mfma<<<gf, 256, 0, stream>>>(qb, kb, vb, mask, ctxb);

    // 3) output projection (bf16 A/B, fp32 out)
    dim3 go(MROWS / 128, DIM / 128);
    gemm_out_mfma<<<go, 256, 0, stream>>>(ctxb, wob, bo, out);
}